// Round 15
// baseline (2513.439 us; speedup 1.0000x reference)
//
#include <hip/hip_runtime.h>
#include <math.h>

#define H 2048
#define IDIM 5632
#define NE 8
#define TT 2048            // tokens = 2*1024
#define LDW1 (2 * IDIM)    // 11264
#define NK1 (H / 64)       // 32
#define NK2 (IDIM / 64)    // 88

typedef __bf16 bf16x8 __attribute__((ext_vector_type(8)));
typedef float f32x4 __attribute__((ext_vector_type(4)));

__device__ __forceinline__ unsigned short f2bf(float f) {
    unsigned int u = __builtin_bit_cast(unsigned int, f);
    u += 0x7FFFu + ((u >> 16) & 1u);   // round-to-nearest-even
    return (unsigned short)(u >> 16);
}

// HW convert: compiler emits v_cvt_pk_bf16_f32 from paired casts (RTNE)
__device__ __forceinline__ unsigned int pk2(float a, float b) {
    __bf16 x = (__bf16)a, y = (__bf16)b;
    unsigned short lo = __builtin_bit_cast(unsigned short, x);
    unsigned short hi = __builtin_bit_cast(unsigned short, y);
    return (unsigned int)lo | ((unsigned int)hi << 16);
}

__device__ __forceinline__ void gload_lds16(const void* g, void* l) {
    __builtin_amdgcn_global_load_lds(
        (const __attribute__((address_space(1))) void*)g,
        (__attribute__((address_space(3))) void*)l, 16, 0, 0);
}

// 32 dword loads: 8 k-rows x 4 spread cols (static indices only)
#define LDB_T(BR, KT)                                                    \
    {                                                                    \
        _Pragma("unroll")                                                \
        for (int r_ = 0; r_ < 8; ++r_) {                                 \
            _Pragma("unroll")                                            \
            for (int j_ = 0; j_ < 4; ++j_)                               \
                BR[r_][j_] = bp[j_][(size_t)((KT) * 64 + r_) * BST];     \
        }                                                                \
    }
// cvt+pack+swizzled b128 writes, 4 chunks (conflict-free, r12-verified)
#define WRB_T(BR, NB)                                                    \
    {                                                                    \
        char* pbw_ = (char*)lds_b[NB];                                   \
        _Pragma("unroll")                                                \
        for (int j_ = 0; j_ < 4; ++j_) {                                 \
            uint4 pk_;                                                   \
            pk_.x = pk2(BR[0][j_], BR[1][j_]);                           \
            pk_.y = pk2(BR[2][j_], BR[3][j_]);                           \
            pk_.z = pk2(BR[4][j_], BR[5][j_]);                           \
            pk_.w = pk2(BR[6][j_], BR[7][j_]);                           \
            *reinterpret_cast<uint4*>(pbw_ + bwaddr[j_]) = pk_;          \
        }                                                                \
    }

// single-barrier fold K-tile. BRC holds B(t+1) (written to nbuf); BRN <- B(t+2).
#define TILE_S(T, BRC, BRN, LD2, VB)                                     \
    {                                                                    \
        const int buf_ = (T) & 1, nbuf_ = buf_ ^ 1;                      \
        issueA((T) + 1, nbuf_);                                          \
        if (LD2) LDB_T(BRN, (T) + 2)                                     \
        compute(buf_);                                                   \
        WRB_T(BRC, nbuf_)                                                \
        asm volatile("s_waitcnt vmcnt(" VB ") lgkmcnt(0)" ::: "memory"); \
        __builtin_amdgcn_sched_barrier(0);                               \
        __builtin_amdgcn_s_barrier();                                    \
        __builtin_amdgcn_sched_barrier(0);                               \
    }

// ---------------- x (fp32) -> bf16 ----------------
__global__ void cvt_x_kernel(const float* __restrict__ x, unsigned short* __restrict__ xb) {
    int i = blockIdx.x * blockDim.x + threadIdx.x;
    float4 v = reinterpret_cast<const float4*>(x)[i];
    ushort4 o;
    o.x = f2bf(v.x); o.y = f2bf(v.y); o.z = f2bf(v.z); o.w = f2bf(v.w);
    reinterpret_cast<ushort4*>(xb)[i] = o;
}

// ---------------- router: fp64 logits, softmax, top-2, lists ----------------
__global__ void router_kernel(const float* __restrict__ x, const float* __restrict__ gw,
                              float* __restrict__ topw, int* __restrict__ cnt,
                              int* __restrict__ list) {
    int t = blockIdx.x;
    int lane = threadIdx.x;
    const float* xt = x + (size_t)t * H;
    double acc[NE];
#pragma unroll
    for (int e = 0; e < NE; ++e) acc[e] = 0.0;
    for (int h = lane; h < H; h += 64) {
        float xv = xt[h];
#pragma unroll
        for (int e = 0; e < NE; ++e) acc[e] += (double)xv * (double)gw[e * H + h];
    }
#pragma unroll
    for (int e = 0; e < NE; ++e) {
#pragma unroll
        for (int off = 32; off > 0; off >>= 1)
            acc[e] += __shfl_xor(acc[e], off, 64);
    }
    if (lane == 0) {
        double mx = acc[0];
#pragma unroll
        for (int e = 1; e < NE; ++e) mx = acc[e] > mx ? acc[e] : mx;
        double ex[NE], s = 0.0;
#pragma unroll
        for (int e = 0; e < NE; ++e) { ex[e] = exp(acc[e] - mx); s += ex[e]; }
        int e0 = 0; double b0 = ex[0];
#pragma unroll
        for (int e = 1; e < NE; ++e) if (ex[e] > b0) { b0 = ex[e]; e0 = e; }
        int e1 = -1; double b1 = -1.0;
#pragma unroll
        for (int e = 0; e < NE; ++e) if (e != e0 && ex[e] > b1) { b1 = ex[e]; e1 = e; }
        float p0 = (float)(b0 / s), p1 = (float)(b1 / s);
        float w0 = p0 / (p0 + p1), w1 = p1 / (p0 + p1);
        topw[t * 2 + 0] = w0;
        topw[t * 2 + 1] = w1;
        int pos0 = atomicAdd(&cnt[e0], 1); list[e0 * TT + pos0] = t * 2 + 0;
        int pos1 = atomicAdd(&cnt[e1], 1); list[e1 * TT + pos1] = t * 2 + 1;
    }
}

// ---------------- tile map (256-row tiles at [20..39]) ----------------
__global__ void setup_kernel(const int* __restrict__ cnt, int* __restrict__ tmap) {
    if (threadIdx.x == 0) {
        int a128 = 0, a256 = 0;
        tmap[0] = 0; tmap[20] = 0;
        for (int g = 0; g < 9; ++g) {
            int rows = (g == 0) ? TT : cnt[g - 1];
            tmap[10 + g] = rows;
            tmap[30 + g] = rows;
            a128 += (rows + 127) >> 7;
            a256 += (rows + 255) >> 8;
            tmap[g + 1] = a128;
            tmap[20 + g + 1] = a256;
        }
        tmap[19] = 0; tmap[39] = 0;
    }
}

// ============ grouped GEMM1: 256x256, BK=64, fold-convert, single-barrier/K-tile ======
__global__ __launch_bounds__(512)
void gemm1_kernel(const unsigned short* __restrict__ xb,
                  const float* __restrict__ base_gu,
                  const float* __restrict__ exp_gu,
                  const int* __restrict__ tmap,
                  const int* __restrict__ list,
                  unsigned short* __restrict__ actB,
                  unsigned short* __restrict__ actE) {
    __shared__ unsigned short lds_a[2][256 * 64];
    __shared__ unsigned short lds_b[2][256 * 64];
    __shared__ int s_arow[256];
    __shared__ int s_orow[256];
    __shared__ int sh[20];

    int tid = threadIdx.x;
    if (tid < 20) sh[tid] = tmap[20 + tid];
    __syncthreads();
    int bid = blockIdx.x;
    int virt = (bid & 7) * 176 + (bid >> 3);     // 1408 = 8*176; jcols contiguous per XCD
    int jcol = virt >> 5;                        // 0..43
    int rt = virt & 31;
    if (rt >= sh[9]) return;
    int g = 0;
    while (rt >= sh[g + 1]) ++g;
    int rows_g = sh[10 + g];
    int row0 = (rt - sh[g]) * 256;
    int n0a = jcol * 128;                        // act-col base

    if (tid < 256) {
        int r = row0 + tid;
        int arow = 0, orow = 0;
        if (r < rows_g) {
            if (g == 0) { arow = r; orow = r; }
            else { int e = list[(g - 1) * TT + r]; arow = e >> 1; orow = e; }
        }
        s_arow[tid] = arow;
        s_orow[tid] = orow;
    }
    __syncthreads();

    const float* W = (g == 0) ? base_gu : (exp_gu + (size_t)(g - 1) * H * LDW1);
    unsigned short* actPtr = (g == 0) ? actB : actE;
    const size_t BST = LDW1;

    // A staging sources (4 gloads/tile; chunk = i*512+tid -> row=chunk>>3, kc=chunk&7)
    const unsigned short* asrc[4];
#pragma unroll
    for (int i = 0; i < 4; ++i) {
        int chunk = i * 512 + tid;
        int rl = chunk >> 3, kc = chunk & 7;
        asrc[i] = xb + (size_t)s_arow[rl] * H + ((kc ^ (rl & 7)) << 3);
    }
    int dstoff = (tid >> 6) * 1024;

    // B fp32 staging: ks = wave (k-rows ks*8..+7), cb = lane; 4 spread cols
    int ks = tid >> 6, cb = tid & 63;
    const float* bp[4];
    int bwaddr[4];
#pragma unroll
    for (int j = 0; j < 4; ++j) {
        int rl = cb + 64 * j;
        int wcol = (((rl >> 5) & 1) ? IDIM : 0) + n0a + ((rl >> 6) << 5) + (rl & 31);
        bp[j] = W + (size_t)(ks * 8) * LDW1 + wcol;
        bwaddr[j] = rl * 128 + ((ks ^ (cb & 7)) << 4);
    }

    auto issueA = [&](int kt, int buf) {
#pragma unroll
        for (int i = 0; i < 4; ++i)
            gload_lds16(asrc[i] + kt * 64, (char*)lds_a[buf] + i * 8192 + dstoff);
    };

    int wave = tid >> 6, lane = tid & 63;
    int wr = wave >> 2, wc = wave & 3;
    int arow0 = wr * 128 + (lane & 15);
    int bcol0 = wc * 64 + (lane & 15);
    int lxor = lane & 7;
    int kq = lane >> 4;

    f32x4 acc[8][4];
#pragma unroll
    for (int fm = 0; fm < 8; ++fm)
#pragma unroll
        for (int fn = 0; fn < 4; ++fn)
            acc[fm][fn] = (f32x4)(0.0f);

    auto compute = [&](int buf) {
        const char* pa = (const char*)lds_a[buf];
        const char* pb = (const char*)lds_b[buf];
        __builtin_amdgcn_s_setprio(1);
#pragma unroll
        for (int kh = 0; kh < 2; ++kh) {
            int slot = ((kq + kh * 4) ^ lxor) << 4;
            bf16x8 bF[4], aF[8];
#pragma unroll
            for (int fn = 0; fn < 4; ++fn)
                bF[fn] = *reinterpret_cast<const bf16x8*>(pb + (bcol0 + fn * 16) * 128 + slot);
#pragma unroll
            for (int i = 0; i < 8; ++i)
                aF[i] = *reinterpret_cast<const bf16x8*>(pa + (arow0 + i * 16) * 128 + slot);
#pragma unroll
            for (int i = 0; i < 8; ++i)
#pragma unroll
                for (int fn = 0; fn < 4; ++fn)
                    acc[i][fn] = __builtin_amdgcn_mfma_f32_16x16x32_bf16(
                        aF[i], bF[fn], acc[i][fn], 0, 0, 0);
        }
        __builtin_amdgcn_s_setprio(0);
    };

    float brA[8][4], brB[8][4];

    // prologue: A(0)+B(0) staged; B(1) in brA
    issueA(0, 0);
    LDB_T(brB, 0)
    WRB_T(brB, 0)                    // implicit reg-dep wait drains B(0) (+older A(0))
    LDB_T(brA, 1)
    asm volatile("s_waitcnt lgkmcnt(0)" ::: "memory");
    __builtin_amdgcn_sched_barrier(0);
    __builtin_amdgcn_s_barrier();
    __builtin_amdgcn_sched_barrier(0);

    for (int t = 0; t + 3 < NK1; t += 2) {
        TILE_S(t, brA, brB, true, "32")
        TILE_S(t + 1, brB, brA, true, "32")
    }
    TILE_S(NK1 - 2, brA, brB, false, "0")
    compute((NK1 - 1) & 1);

    int cq = lane >> 4, cr = lane & 15;
#pragma unroll
    for (int fm = 0; fm < 8; ++fm) {
#pragma unroll
        for (int r = 0; r < 4; ++r) {
            int rloc = wr * 128 + fm * 16 + cq * 4 + r;
            if (row0 + rloc < rows_g) {
                size_t orow = (size_t)s_orow[rloc];
#pragma unroll
                for (int fn = 0; fn < 2; ++fn) {
                    float gv = acc[fm][fn][r];
                    float uv = acc[fm][fn + 2][r];
                    float sv = gv / (1.0f + __expf(-gv));
                    int col = n0a + wc * 32 + fn * 16 + cr;
                    actPtr[orow * IDIM + col] = f2bf(sv * uv);
                }
            }
        }
    }
}

// ============ grouped GEMM2: 256x256, BK=64, fold-convert, single-barrier/K-tile ======
__global__ __launch_bounds__(512)
void gemm2_kernel(const unsigned short* __restrict__ actB,
                  const unsigned short* __restrict__ actE,
                  const float* __restrict__ base_dn,
                  const float* __restrict__ exp_dn,
                  const int* __restrict__ tmap,
                  const int* __restrict__ list,
                  float* __restrict__ outB,
                  float* __restrict__ yslot) {
    __shared__ unsigned short lds_a[2][256 * 64];
    __shared__ unsigned short lds_b[2][256 * 64];
    __shared__ int s_row[256];
    __shared__ int sh[20];

    int tid = threadIdx.x;
    if (tid < 20) sh[tid] = tmap[20 + tid];
    __syncthreads();
    int bid = blockIdx.x;
    int virt = (bid & 7) * 32 + (bid >> 3);      // 256 = 8*32; one col-strip per XCD
    int jcol = virt >> 5;                        // 0..7
    int rt = virt & 31;
    if (rt >= sh[9]) return;
    int g = 0;
    while (rt >= sh[g + 1]) ++g;
    int rows_g = sh[10 + g];
    int row0 = (rt - sh[g]) * 256;
    int n0 = jcol * 256;

    if (tid < 256) {
        int r = row0 + tid;
        int rowi = 0;
        if (r < rows_g) rowi = (g == 0) ? r : list[(g - 1) * TT + r];
        s_row[tid] = rowi;
    }
    __syncthreads();

    const unsigned short* abase = (g == 0) ? actB : actE;
    const float* W = (g == 0) ? base_dn : (exp_dn + (size_t)(g - 1) * IDIM * H);
    float* obase = (g == 0) ? outB : yslot;
    const size_t BST = H;

    const unsigned short* asrc[4];
#pragma unroll
    for (int i = 0; i < 4; ++i) {
        int chunk = i * 512 + tid;
        int rl = chunk >> 3, kc = chunk & 7;
        asrc[i] = abase + (size_t)s_row[rl] * IDIM + ((kc ^ (rl & 7)) << 3);
    }
    int dstoff = (tid >> 6) * 1024;

    int ks = tid >> 6, cb = tid & 63;
    const float* bp[4];
    int bwaddr[4];
#pragma unroll
    for (int j = 0; j < 4; ++j) {
        int rl = cb + 64 * j;
        bp[j] = W + (size_t)(ks * 8) * H + n0 + rl;
        bwaddr[j] = rl * 128 + ((ks ^ (cb & 7)) << 4);
    }

    auto issueA = [&](int kt, int buf) {
#pragma unroll
        for (int i = 0; i < 4; ++i)
            gload_lds16(asrc[i] + kt * 64, (char*)lds_a[buf] + i * 8192 + dstoff);
    };

    int wave = tid >> 6, lane = tid & 63;
    int wr = wave >> 2, wc = wave & 3;
    int arow0 = wr * 128 + (lane & 15);
    int bcol0 = wc * 64 + (lane & 15);
    int lxor = lane & 7;
    int kq = lane >> 4;

    f32x4 acc[8][4];
#pragma unroll
    for (int fm = 0; fm < 8; ++fm)
#pragma unroll
        for (int fn = 0; fn < 4; ++fn)
            acc[fm][fn] = (f32x4)(0.0f);

    auto compute = [&](int buf) {
        const char* pa = (const char*)lds_a[buf];
        const char* pb = (const char*)lds_b[buf];
        __builtin_amdgcn_s_setprio(1);
#pragma unroll
        for (int kh = 0; kh < 2; ++kh) {
            int slot = ((kq + kh * 4) ^ lxor) << 4;
            bf16x8 bF[4], aF[8];
#pragma unroll
            for (int fn = 0; fn < 4; ++fn)
                bF[fn] = *reinterpret_cast<const bf16x8*>(pb + (bcol0 + fn * 16) * 128 + slot);
#pragma unroll
            for (int i = 0; i < 8; ++i)
                aF[i] = *reinterpret_cast<const bf16x8*>(pa + (arow0 + i * 16) * 128 + slot);
#pragma unroll
            for (int i = 0; i < 8; ++i)
#pragma unroll
                for (int fn = 0; fn < 4; ++fn)
                    acc[i][fn] = __builtin_amdgcn_mfma_f32_16x16x32_bf16(
                        aF[i], bF[fn], acc[i][fn], 0, 0, 0);
        }
        __builtin_amdgcn_s_setprio(0);
    };

    float brA[8][4], brB[8][4];

    issueA(0, 0);
    LDB_T(brB, 0)
    WRB_T(brB, 0)
    LDB_T(brA, 1)
    asm volatile("s_waitcnt lgkmcnt(0)" ::: "memory");
    __builtin_amdgcn_sched_barrier(0);
    __builtin_amdgcn_s_barrier();
    __builtin_amdgcn_sched_barrier(0);

    for (int t = 0; t + 3 < NK2; t += 2) {
        TILE_S(t, brA, brB, true, "32")
        TILE_S(t + 1, brB, brA, true, "32")
    }
    TILE_S(NK2 - 2, brA, brB, false, "0")
    compute((NK2 - 1) & 1);

    int cq = lane >> 4, cr = lane & 15;
#pragma unroll
    for (int fm = 0; fm < 8; ++fm) {
#pragma unroll
        for (int r = 0; r < 4; ++r) {
            int rloc = wr * 128 + fm * 16 + cq * 4 + r;
            if (row0 + rloc < rows_g) {
                size_t orow = (size_t)s_row[rloc];
#pragma unroll
                for (int fn = 0; fn < 4; ++fn) {
                    int col = n0 + wc * 64 + fn * 16 + cr;
                    obase[orow * H + col] = acc[fm][fn][r];
                }
            }
        }
    }
}

// ---------------- combine: out += w0*y0 + w1*y1 ----------------
__global__ void combine_kernel(float* __restrict__ out, const float* __restrict__ yslot,
                               const float* __restrict__ topw) {
    int i = blockIdx.x * blockDim.x + threadIdx.x;
    int t = i >> 9;
    int c = (i & 511) << 2;
    float w0 = topw[t * 2], w1 = topw[t * 2 + 1];
    float4 y0 = *reinterpret_cast<const float4*>(yslot + ((size_t)(2 * t) * H + c));
    float4 y1 = *reinterpret_cast<const float4*>(yslot + ((size_t)(2 * t + 1) * H + c));
    float4* po = reinterpret_cast<float4*>(out + ((size_t)t * H + c));
    float4 o = *po;
    o.x += w0 * y0.x + w1 * y1.x;
    o.y += w0 * y0.y + w1 * y1.y;
    o.z += w0 * y0.z + w1 * y1.z;
    o.w += w0 * y0.w + w1 * y1.w;
    *po = o;
}

extern "C" void kernel_launch(void* const* d_in, const int* in_sizes, int n_in,
                              void* d_out, int out_size, void* d_ws, size_t ws_size,
                              hipStream_t stream) {
    const float* x   = (const float*)d_in[0];
    const float* gw  = (const float*)d_in[1];
    const float* bgu = (const float*)d_in[2];
    const float* bdn = (const float*)d_in[3];
    const float* egu = (const float*)d_in[4];
    const float* edn = (const float*)d_in[5];
    float* out = (float*)d_out;
    char* ws = (char*)d_ws;

    unsigned short* xb   = (unsigned short*)(ws + 0);          //  8,388,608 B
    unsigned short* actB = (unsigned short*)(ws + 8388608);    // 23,068,672 B
    unsigned short* actE = (unsigned short*)(ws + 31457280);   // 46,137,344 B
    float* yslot         = (float*)(ws + 77594624);            // 33,554,432 B
    float* topw          = (float*)(ws + 111149056);
    int* cnt             = (int*)(ws + 111165440);
    int* list            = (int*)(ws + 111165696);
    int* tmap            = (int*)(ws + 111231232);

    hipMemsetAsync(cnt, 0, NE * sizeof(int), stream);
    cvt_x_kernel<<<4096, 256, 0, stream>>>(x, xb);
    router_kernel<<<TT, 64, 0, stream>>>(x, gw, topw, cnt, list);
    setup_kernel<<<1, 64, 0, stream>>>(cnt, tmap);
    // gemm1: 44 col-strips x up-to-32 row-tiles, XCD-pinned
    gemm1_kernel<<<1408, 512, 0, stream>>>(xb, bgu, egu, tmap, list, actB, actE);
    // gemm2: 8 col-strips x up-to-32 row-tiles
    gemm2_kernel<<<256, 512, 0, stream>>>(actB, actE, bdn, edn, tmap, list, out, yslot);
    combine_kernel<<<4096, 256, 0, stream>>>(out, yslot, topw);
}

// Round 16
// 922.142 us; speedup vs baseline: 2.7257x; 2.7257x over previous
//
#include <hip/hip_runtime.h>
#include <math.h>

#define H 2048
#define IDIM 5632
#define NE 8
#define TT 2048            // tokens = 2*1024
#define LDW1 (2 * IDIM)    // 11264
#define NK1 (H / 64)       // 32
#define NK2 (IDIM / 64)    // 88

typedef __bf16 bf16x8 __attribute__((ext_vector_type(8)));
typedef float f32x16 __attribute__((ext_vector_type(16)));

__device__ __forceinline__ unsigned short f2bf(float f) {
    unsigned int u = __builtin_bit_cast(unsigned int, f);
    u += 0x7FFFu + ((u >> 16) & 1u);   // round-to-nearest-even
    return (unsigned short)(u >> 16);
}

// HW convert: compiler emits v_cvt_pk_bf16_f32 from paired casts (RTNE)
__device__ __forceinline__ unsigned int pk2(float a, float b) {
    __bf16 x = (__bf16)a, y = (__bf16)b;
    unsigned short lo = __builtin_bit_cast(unsigned short, x);
    unsigned short hi = __builtin_bit_cast(unsigned short, y);
    return (unsigned int)lo | ((unsigned int)hi << 16);
}

__device__ __forceinline__ void gload_lds16(const void* g, void* l) {
    __builtin_amdgcn_global_load_lds(
        (const __attribute__((address_space(1))) void*)g,
        (__attribute__((address_space(3))) void*)l, 16, 0, 0);
}

#define PH_OPEN                                         \
    __builtin_amdgcn_s_barrier();                       \
    asm volatile("s_waitcnt lgkmcnt(0)" ::: "memory");  \
    __builtin_amdgcn_sched_barrier(0);                  \
    __builtin_amdgcn_s_setprio(1);
#define PH_CL                                           \
    __builtin_amdgcn_s_setprio(0);                      \
    __builtin_amdgcn_sched_barrier(0);                  \
    __builtin_amdgcn_s_barrier();

// 16 dword loads: rows rlo..rlo+3 x 4 spread cols (static indices only)
#define LDB_HALF(BR, kt, rlo)                                            \
    {                                                                    \
        _Pragma("unroll")                                                \
        for (int r_ = 0; r_ < 4; ++r_) {                                 \
            _Pragma("unroll")                                            \
            for (int j_ = 0; j_ < 4; ++j_)                               \
                BR[(rlo) + r_][j_] =                                     \
                    bp[j_][(size_t)((kt) * 64 + (rlo) + r_) * BST];      \
        }                                                                \
    }
// cvt+pack+swizzled b128 writes, chunks jlo..jlo+1 (conflict-free, r12-verified)
#define WRB_HALF(BR, nb, jlo)                                            \
    {                                                                    \
        char* pbw_ = (char*)lds_b[nb];                                   \
        _Pragma("unroll")                                                \
        for (int j_ = (jlo); j_ < (jlo) + 2; ++j_) {                     \
            uint4 pk_;                                                   \
            pk_.x = pk2(BR[0][j_], BR[1][j_]);                           \
            pk_.y = pk2(BR[2][j_], BR[3][j_]);                           \
            pk_.z = pk2(BR[4][j_], BR[5][j_]);                           \
            pk_.w = pk2(BR[6][j_], BR[7][j_]);                           \
            *reinterpret_cast<uint4*>(pbw_ + bwaddr[j_]) = pk_;          \
        }                                                                \
    }

// per-kstep fragment reads: all 6 b128 reads share one swizzle slot
#define RDAB(KS)                                                         \
    {                                                                    \
        int slot_ = ((((KS) << 1) | khi) ^ l7) << 4;                     \
        aF[0] = *reinterpret_cast<const bf16x8*>(pa_ + aB0 + slot_);     \
        aF[1] = *reinterpret_cast<const bf16x8*>(pa_ + aB1 + slot_);     \
        aF[2] = *reinterpret_cast<const bf16x8*>(pa_ + aB2 + slot_);     \
        aF[3] = *reinterpret_cast<const bf16x8*>(pa_ + aB3 + slot_);     \
        bF[0] = *reinterpret_cast<const bf16x8*>(pb_ + bB0 + slot_);     \
        bF[1] = *reinterpret_cast<const bf16x8*>(pb_ + bB1 + slot_);     \
    }
#define MFMA8                                                            \
    _Pragma("unroll")                                                    \
    for (int i_ = 0; i_ < 4; ++i_) {                                     \
        acc[i_][0] = __builtin_amdgcn_mfma_f32_32x32x16_bf16(            \
            aF[i_], bF[0], acc[i_][0], 0, 0, 0);                         \
        acc[i_][1] = __builtin_amdgcn_mfma_f32_32x32x16_bf16(            \
            aF[i_], bF[1], acc[i_][1], 0, 0, 0);                         \
    }

// 4-phase fold K-tile (r12 schedule). BRC holds B(t+1) (write to nbuf); BRN <- B(t+2).
#define TILE_F(T, BRC, BRN, DO_STA, DO_LDB, DO_WR, VB)                   \
    {                                                                    \
        const int buf_ = (T) & 1, nbuf_ = buf_ ^ 1;                      \
        const char* pa_ = (const char*)lds_a[buf_];                      \
        const char* pb_ = (const char*)lds_b[buf_];                      \
        RDAB(0)                                                          \
        if (DO_STA) issueA((T) + 1, nbuf_);                              \
        if (DO_LDB) LDB_HALF(BRN, (T) + 2, 0)                            \
        PH_OPEN; MFMA8 PH_CL                                             \
        RDAB(1)                                                          \
        if (DO_WR) WRB_HALF(BRC, nbuf_, 0)                               \
        PH_OPEN; MFMA8 PH_CL                                             \
        RDAB(2)                                                          \
        if (DO_LDB) LDB_HALF(BRN, (T) + 2, 4)                            \
        PH_OPEN; MFMA8 PH_CL                                             \
        RDAB(3)                                                          \
        if (DO_WR) WRB_HALF(BRC, nbuf_, 2)                               \
        __builtin_amdgcn_s_barrier();                                    \
        asm volatile("s_waitcnt lgkmcnt(0)" ::: "memory");               \
        __builtin_amdgcn_sched_barrier(0);                               \
        __builtin_amdgcn_s_setprio(1);                                   \
        MFMA8                                                            \
        __builtin_amdgcn_s_setprio(0);                                   \
        __builtin_amdgcn_sched_barrier(0);                               \
        asm volatile("s_waitcnt vmcnt(" VB ")" ::: "memory");            \
        __builtin_amdgcn_sched_barrier(0);                               \
        __builtin_amdgcn_s_barrier();                                    \
        __builtin_amdgcn_sched_barrier(0);                               \
    }

// ---------------- x (fp32) -> bf16 ----------------
__global__ void cvt_x_kernel(const float* __restrict__ x, unsigned short* __restrict__ xb) {
    int i = blockIdx.x * blockDim.x + threadIdx.x;
    float4 v = reinterpret_cast<const float4*>(x)[i];
    ushort4 o;
    o.x = f2bf(v.x); o.y = f2bf(v.y); o.z = f2bf(v.z); o.w = f2bf(v.w);
    reinterpret_cast<ushort4*>(xb)[i] = o;
}

// ---------------- router: fp64 logits, softmax, top-2, lists ----------------
__global__ void router_kernel(const float* __restrict__ x, const float* __restrict__ gw,
                              float* __restrict__ topw, int* __restrict__ cnt,
                              int* __restrict__ list) {
    int t = blockIdx.x;
    int lane = threadIdx.x;
    const float* xt = x + (size_t)t * H;
    double acc[NE];
#pragma unroll
    for (int e = 0; e < NE; ++e) acc[e] = 0.0;
    for (int h = lane; h < H; h += 64) {
        float xv = xt[h];
#pragma unroll
        for (int e = 0; e < NE; ++e) acc[e] += (double)xv * (double)gw[e * H + h];
    }
#pragma unroll
    for (int e = 0; e < NE; ++e) {
#pragma unroll
        for (int off = 32; off > 0; off >>= 1)
            acc[e] += __shfl_xor(acc[e], off, 64);
    }
    if (lane == 0) {
        double mx = acc[0];
#pragma unroll
        for (int e = 1; e < NE; ++e) mx = acc[e] > mx ? acc[e] : mx;
        double ex[NE], s = 0.0;
#pragma unroll
        for (int e = 0; e < NE; ++e) { ex[e] = exp(acc[e] - mx); s += ex[e]; }
        int e0 = 0; double b0 = ex[0];
#pragma unroll
        for (int e = 1; e < NE; ++e) if (ex[e] > b0) { b0 = ex[e]; e0 = e; }
        int e1 = -1; double b1 = -1.0;
#pragma unroll
        for (int e = 0; e < NE; ++e) if (e != e0 && ex[e] > b1) { b1 = ex[e]; e1 = e; }
        float p0 = (float)(b0 / s), p1 = (float)(b1 / s);
        float w0 = p0 / (p0 + p1), w1 = p1 / (p0 + p1);
        topw[t * 2 + 0] = w0;
        topw[t * 2 + 1] = w1;
        int pos0 = atomicAdd(&cnt[e0], 1); list[e0 * TT + pos0] = t * 2 + 0;
        int pos1 = atomicAdd(&cnt[e1], 1); list[e1 * TT + pos1] = t * 2 + 1;
    }
}

// ---------------- tile map (256-row tiles at [20..39]) ----------------
__global__ void setup_kernel(const int* __restrict__ cnt, int* __restrict__ tmap) {
    if (threadIdx.x == 0) {
        int a128 = 0, a256 = 0;
        tmap[0] = 0; tmap[20] = 0;
        for (int g = 0; g < 9; ++g) {
            int rows = (g == 0) ? TT : cnt[g - 1];
            tmap[10 + g] = rows;
            tmap[30 + g] = rows;
            a128 += (rows + 127) >> 7;
            a256 += (rows + 255) >> 8;
            tmap[g + 1] = a128;
            tmap[20 + g + 1] = a256;
        }
        tmap[19] = 0; tmap[39] = 0;
    }
}

// ============ grouped GEMM1: 256x256, BK=64, fold-convert, 4-phase, 32x32 MFMA ========
__global__ __launch_bounds__(512)
void gemm1_kernel(const unsigned short* __restrict__ xb,
                  const float* __restrict__ base_gu,
                  const float* __restrict__ exp_gu,
                  const int* __restrict__ tmap,
                  const int* __restrict__ list,
                  unsigned short* __restrict__ actB,
                  unsigned short* __restrict__ actE) {
    __shared__ unsigned short lds_a[2][256 * 64];
    __shared__ unsigned short lds_b[2][256 * 64];
    __shared__ int s_arow[256];
    __shared__ int s_orow[256];
    __shared__ int sh[20];

    int tid = threadIdx.x;
    if (tid < 20) sh[tid] = tmap[20 + tid];
    __syncthreads();
    int bid = blockIdx.x;
    int virt = (bid & 7) * 176 + (bid >> 3);     // 1408 = 8*176; jcols contiguous per XCD
    int jcol = virt >> 5;                        // 0..43
    int rt = virt & 31;
    if (rt >= sh[9]) return;
    int g = 0;
    while (rt >= sh[g + 1]) ++g;
    int rows_g = sh[10 + g];
    int row0 = (rt - sh[g]) * 256;
    int n0a = jcol * 128;                        // act-col base

    if (tid < 256) {
        int r = row0 + tid;
        int arow = 0, orow = 0;
        if (r < rows_g) {
            if (g == 0) { arow = r; orow = r; }
            else { int e = list[(g - 1) * TT + r]; arow = e >> 1; orow = e; }
        }
        s_arow[tid] = arow;
        s_orow[tid] = orow;
    }
    __syncthreads();

    const float* W = (g == 0) ? base_gu : (exp_gu + (size_t)(g - 1) * H * LDW1);
    unsigned short* actPtr = (g == 0) ? actB : actE;
    const size_t BST = LDW1;

    // A staging sources (4 gloads/tile; chunk = i*512+tid -> row=chunk>>3, kc=chunk&7)
    const unsigned short* asrc[4];
#pragma unroll
    for (int i = 0; i < 4; ++i) {
        int chunk = i * 512 + tid;
        int rl = chunk >> 3, kc = chunk & 7;
        asrc[i] = xb + (size_t)s_arow[rl] * H + ((kc ^ (rl & 7)) << 3);
    }
    int dstoff = (tid >> 6) * 1024;

    // B fp32 staging: ks = wave (k-rows ks*8..+7), cb = lane; 4 spread cols
    int ksv = tid >> 6, cb = tid & 63;
    const float* bp[4];
    int bwaddr[4];
#pragma unroll
    for (int j = 0; j < 4; ++j) {
        int rl = cb + 64 * j;
        int wcol = (((rl >> 5) & 1) ? IDIM : 0) + n0a + ((rl >> 6) << 5) + (rl & 31);
        bp[j] = W + (size_t)(ksv * 8) * LDW1 + wcol;
        bwaddr[j] = rl * 128 + ((ksv ^ (cb & 7)) << 4);
    }

    auto issueA = [&](int kt, int buf) {
#pragma unroll
        for (int i = 0; i < 4; ++i)
            gload_lds16(asrc[i] + kt * 64, (char*)lds_a[buf] + i * 8192 + dstoff);
    };

    int wave = tid >> 6, lane = tid & 63;
    int wr = wave >> 2, wc = wave & 3;           // 2M x 4N; wave tile 128 x 64
    int l31 = lane & 31, khi = lane >> 5, l7 = lane & 7;
    int aB0 = (wr * 128 + 0 * 32 + l31) * 128;
    int aB1 = (wr * 128 + 1 * 32 + l31) * 128;
    int aB2 = (wr * 128 + 2 * 32 + l31) * 128;
    int aB3 = (wr * 128 + 3 * 32 + l31) * 128;
    int bB0 = (wc * 64 + 0 + l31) * 128;
    int bB1 = (wc * 64 + 32 + l31) * 128;

    f32x16 acc[4][2];
#pragma unroll
    for (int fm = 0; fm < 4; ++fm)
#pragma unroll
        for (int fn = 0; fn < 2; ++fn)
            acc[fm][fn] = (f32x16)(0.0f);

    bf16x8 aF[4], bF[2];
    float brA[8][4], brB[8][4];

    // prologue: A(0)+B(0) staged; B(1) in brA
    issueA(0, 0);
    LDB_HALF(brB, 0, 0) LDB_HALF(brB, 0, 4)
    WRB_HALF(brB, 0, 0) WRB_HALF(brB, 0, 2)     // implicit waits drain B(0)+older A(0)
    LDB_HALF(brA, 1, 0) LDB_HALF(brA, 1, 4)
    asm volatile("s_waitcnt lgkmcnt(0)" ::: "memory");
    __builtin_amdgcn_sched_barrier(0);
    __builtin_amdgcn_s_barrier();
    __builtin_amdgcn_sched_barrier(0);

    for (int t = 0; t + 3 < NK1; t += 2) {
        TILE_F(t, brA, brB, true, true, true, "32")
        TILE_F(t + 1, brB, brA, true, true, true, "32")
    }
    TILE_F(NK1 - 2, brA, brB, true, false, true, "0")
    TILE_F(NK1 - 1, brB, brA, false, false, false, "63")

    int rbase = khi << 2;
#pragma unroll
    for (int fm = 0; fm < 4; ++fm) {
#pragma unroll
        for (int r = 0; r < 16; ++r) {
            int rloc = wr * 128 + fm * 32 + (r & 3) + ((r >> 2) << 3) + rbase;
            if (row0 + rloc < rows_g) {
                size_t orow = (size_t)s_orow[rloc];
                float gv = acc[fm][0][r];
                float uv = acc[fm][1][r];
                float sv = gv / (1.0f + __expf(-gv));
                int col = n0a + wc * 32 + l31;
                actPtr[orow * IDIM + col] = f2bf(sv * uv);
            }
        }
    }
}

// ============ grouped GEMM2: 256x256, BK=64, fold-convert, 4-phase, 32x32 MFMA ========
__global__ __launch_bounds__(512)
void gemm2_kernel(const unsigned short* __restrict__ actB,
                  const unsigned short* __restrict__ actE,
                  const float* __restrict__ base_dn,
                  const float* __restrict__ exp_dn,
                  const int* __restrict__ tmap,
                  const int* __restrict__ list,
                  float* __restrict__ outB,
                  float* __restrict__ yslot) {
    __shared__ unsigned short lds_a[2][256 * 64];
    __shared__ unsigned short lds_b[2][256 * 64];
    __shared__ int s_row[256];
    __shared__ int sh[20];

    int tid = threadIdx.x;
    if (tid < 20) sh[tid] = tmap[20 + tid];
    __syncthreads();
    int bid = blockIdx.x;
    int virt = (bid & 7) * 32 + (bid >> 3);      // 256 = 8*32; one col-strip per XCD
    int jcol = virt >> 5;                        // 0..7
    int rt = virt & 31;
    if (rt >= sh[9]) return;
    int g = 0;
    while (rt >= sh[g + 1]) ++g;
    int rows_g = sh[10 + g];
    int row0 = (rt - sh[g]) * 256;
    int n0 = jcol * 256;

    if (tid < 256) {
        int r = row0 + tid;
        int rowi = 0;
        if (r < rows_g) rowi = (g == 0) ? r : list[(g - 1) * TT + r];
        s_row[tid] = rowi;
    }
    __syncthreads();

    const unsigned short* abase = (g == 0) ? actB : actE;
    const float* W = (g == 0) ? base_dn : (exp_dn + (size_t)(g - 1) * IDIM * H);
    float* obase = (g == 0) ? outB : yslot;
    const size_t BST = H;

    const unsigned short* asrc[4];
#pragma unroll
    for (int i = 0; i < 4; ++i) {
        int chunk = i * 512 + tid;
        int rl = chunk >> 3, kc = chunk & 7;
        asrc[i] = abase + (size_t)s_row[rl] * IDIM + ((kc ^ (rl & 7)) << 3);
    }
    int dstoff = (tid >> 6) * 1024;

    int ksv = tid >> 6, cb = tid & 63;
    const float* bp[4];
    int bwaddr[4];
#pragma unroll
    for (int j = 0; j < 4; ++j) {
        int rl = cb + 64 * j;
        bp[j] = W + (size_t)(ksv * 8) * H + n0 + rl;
        bwaddr[j] = rl * 128 + ((ksv ^ (cb & 7)) << 4);
    }

    auto issueA = [&](int kt, int buf) {
#pragma unroll
        for (int i = 0; i < 4; ++i)
            gload_lds16(asrc[i] + kt * 64, (char*)lds_a[buf] + i * 8192 + dstoff);
    };

    int wave = tid >> 6, lane = tid & 63;
    int wr = wave >> 2, wc = wave & 3;
    int l31 = lane & 31, khi = lane >> 5, l7 = lane & 7;
    int aB0 = (wr * 128 + 0 * 32 + l31) * 128;
    int aB1 = (wr * 128 + 1 * 32 + l31) * 128;
    int aB2 = (wr * 128 + 2 * 32 + l31) * 128;
    int aB3 = (wr * 128 + 3 * 32 + l31) * 128;
    int bB0 = (wc * 64 + 0 + l31) * 128;
    int bB1 = (wc * 64 + 32 + l31) * 128;

    f32x16 acc[4][2];
#pragma unroll
    for (int fm = 0; fm < 4; ++fm)
#pragma unroll
        for (int fn = 0; fn < 2; ++fn)
            acc[fm][fn] = (f32x16)(0.0f);

    bf16x8 aF[4], bF[2];
    float brA[8][4], brB[8][4];

    issueA(0, 0);
    LDB_HALF(brB, 0, 0) LDB_HALF(brB, 0, 4)
    WRB_HALF(brB, 0, 0) WRB_HALF(brB, 0, 2)
    LDB_HALF(brA, 1, 0) LDB_HALF(brA, 1, 4)
    asm volatile("s_waitcnt lgkmcnt(0)" ::: "memory");
    __builtin_amdgcn_sched_barrier(0);
    __builtin_amdgcn_s_barrier();
    __builtin_amdgcn_sched_barrier(0);

    for (int t = 0; t + 3 < NK2; t += 2) {
        TILE_F(t, brA, brB, true, true, true, "32")
        TILE_F(t + 1, brB, brA, true, true, true, "32")
    }
    TILE_F(NK2 - 2, brA, brB, true, false, true, "0")
    TILE_F(NK2 - 1, brB, brA, false, false, false, "63")

    int rbase = khi << 2;
#pragma unroll
    for (int fm = 0; fm < 4; ++fm) {
#pragma unroll
        for (int fn = 0; fn < 2; ++fn) {
#pragma unroll
            for (int r = 0; r < 16; ++r) {
                int rloc = wr * 128 + fm * 32 + (r & 3) + ((r >> 2) << 3) + rbase;
                if (row0 + rloc < rows_g) {
                    size_t orow = (size_t)s_row[rloc];
                    int col = n0 + wc * 64 + fn * 32 + l31;
                    obase[orow * H + col] = acc[fm][fn][r];
                }
            }
        }
    }
}

// ---------------- combine: out += w0*y0 + w1*y1 ----------------
__global__ void combine_kernel(float* __restrict__ out, const float* __restrict__ yslot,
                               const float* __restrict__ topw) {
    int i = blockIdx.x * blockDim.x + threadIdx.x;
    int t = i >> 9;
    int c = (i & 511) << 2;
    float w0 = topw[t * 2], w1 = topw[t * 2 + 1];
    float4 y0 = *reinterpret_cast<const float4*>(yslot + ((size_t)(2 * t) * H + c));
    float4 y1 = *reinterpret_cast<const float4*>(yslot + ((size_t)(2 * t + 1) * H + c));
    float4* po = reinterpret_cast<float4*>(out + ((size_t)t * H + c));
    float4 o = *po;
    o.x += w0 * y0.x + w1 * y1.x;
    o.y += w0 * y0.y + w1 * y1.y;
    o.z += w0 * y0.z + w1 * y1.z;
    o.w += w0 * y0.w + w1 * y1.w;
    *po = o;
}

extern "C" void kernel_launch(void* const* d_in, const int* in_sizes, int n_in,
                              void* d_out, int out_size, void* d_ws, size_t ws_size,
                              hipStream_t stream) {
    const float* x   = (const float*)d_in[0];
    const float* gw  = (const float*)d_in[1];
    const float* bgu = (const float*)d_in[2];
    const float* bdn = (const float*)d_in[3];
    const float* egu = (const float*)d_in[4];
    const float* edn = (const float*)d_in[5];
    float* out = (float*)d_out;
    char* ws = (char*)d_ws;

    unsigned short* xb   = (unsigned short*)(ws + 0);          //  8,388,608 B
    unsigned short* actB = (unsigned short*)(ws + 8388608);    // 23,068,672 B
    unsigned short* actE = (unsigned short*)(ws + 31457280);   // 46,137,344 B
    float* yslot         = (float*)(ws + 77594624);            // 33,554,432 B
    float* topw          = (float*)(ws + 111149056);
    int* cnt             = (int*)(ws + 111165440);
    int* list            = (int*)(ws + 111165696);
    int* tmap            = (int*)(ws + 111231232);

    hipMemsetAsync(cnt, 0, NE * sizeof(int), stream);
    cvt_x_kernel<<<4096, 256, 0, stream>>>(x, xb);
    router_kernel<<<TT, 64, 0, stream>>>(x, gw, topw, cnt, list);
    setup_kernel<<<1, 64, 0, stream>>>(cnt, tmap);
    // gemm1: 44 col-strips x up-to-32 row-tiles, XCD-pinned
    gemm1_kernel<<<1408, 512, 0, stream>>>(xb, bgu, egu, tmap, list, actB, actE);
    // gemm2: 8 col-strips x up-to-32 row-tiles
    gemm2_kernel<<<256, 512, 0, stream>>>(actB, actE, bdn, edn, tmap, list, out, yslot);
    combine_kernel<<<4096, 256, 0, stream>>>(out, yslot, topw);
}

// Round 17
// 773.282 us; speedup vs baseline: 3.2504x; 1.1925x over previous
//
#include <hip/hip_runtime.h>
#include <math.h>

#define H 2048
#define IDIM 5632
#define NE 8
#define TT 2048            // tokens = 2*1024
#define LDW1 (2 * IDIM)    // 11264
#define NK1 (H / 64)       // 32
#define NK2 (IDIM / 64)    // 88

typedef __bf16 bf16x8 __attribute__((ext_vector_type(8)));
typedef float f32x4 __attribute__((ext_vector_type(4)));

__device__ __forceinline__ unsigned short f2bf(float f) {
    unsigned int u = __builtin_bit_cast(unsigned int, f);
    u += 0x7FFFu + ((u >> 16) & 1u);   // round-to-nearest-even
    return (unsigned short)(u >> 16);
}

// HW convert: compiler emits v_cvt_pk_bf16_f32 from paired casts (RTNE)
__device__ __forceinline__ unsigned int pk2(float a, float b) {
    __bf16 x = (__bf16)a, y = (__bf16)b;
    unsigned short lo = __builtin_bit_cast(unsigned short, x);
    unsigned short hi = __builtin_bit_cast(unsigned short, y);
    return (unsigned int)lo | ((unsigned int)hi << 16);
}

__device__ __forceinline__ void gload_lds16(const void* g, void* l) {
    __builtin_amdgcn_global_load_lds(
        (const __attribute__((address_space(1))) void*)g,
        (__attribute__((address_space(3))) void*)l, 16, 0, 0);
}

// per-phase fences: wave-local only (no s_barrier; rule #18 sched_barrier after lgkm)
#define PH_OPEN                                         \
    asm volatile("s_waitcnt lgkmcnt(0)" ::: "memory");  \
    __builtin_amdgcn_sched_barrier(0);                  \
    __builtin_amdgcn_s_setprio(1);
#define PH_CL                                           \
    __builtin_amdgcn_s_setprio(0);                      \
    __builtin_amdgcn_sched_barrier(0);

// 16 dword loads: rows rlo..rlo+3 x 4 spread cols (static indices only)
#define LDB_HALF(BR, kt, rlo)                                            \
    {                                                                    \
        _Pragma("unroll")                                                \
        for (int r_ = 0; r_ < 4; ++r_) {                                 \
            _Pragma("unroll")                                            \
            for (int j_ = 0; j_ < 4; ++j_)                               \
                BR[(rlo) + r_][j_] =                                     \
                    bp[j_][(size_t)((kt) * 64 + (rlo) + r_) * BST];      \
        }                                                                \
    }
// cvt+pack+swizzled b128 writes, chunks jlo..jlo+1 (conflict-free, r12-verified)
#define WRB_HALF(BR, nb, jlo)                                            \
    {                                                                    \
        char* pbw_ = (char*)lds_b[nb];                                   \
        _Pragma("unroll")                                                \
        for (int j_ = (jlo); j_ < (jlo) + 2; ++j_) {                     \
            uint4 pk_;                                                   \
            pk_.x = pk2(BR[0][j_], BR[1][j_]);                           \
            pk_.y = pk2(BR[2][j_], BR[3][j_]);                           \
            pk_.z = pk2(BR[4][j_], BR[5][j_]);                           \
            pk_.w = pk2(BR[6][j_], BR[7][j_]);                           \
            *reinterpret_cast<uint4*>(pbw_ + bwaddr[j_]) = pk_;          \
        }                                                                \
    }

// 4-phase fold K-tile, ONE block barrier per tile (boundary only).
// BRC holds B(t+1) (write to nbuf); BRN gets B(t+2).
#define TILE_F(T, BRC, BRN, DO_STA, DO_LDB, DO_WR, VB)                   \
    {                                                                    \
        const int buf_ = (T) & 1, nbuf_ = buf_ ^ 1;                      \
        const char* pa_ = (const char*)lds_a[buf_];                      \
        const char* pb_ = (const char*)lds_b[buf_];                      \
        int slot0_ = (kq ^ lxor) << 4;                                   \
        int slot1_ = ((kq + 4) ^ lxor) << 4;                             \
        rdB(bfr, pb_, slot0_);                                           \
        rdA(a0, pa_, slot0_, 0);                                         \
        if (DO_STA) issueA((T) + 1, nbuf_);                              \
        if (DO_LDB) LDB_HALF(BRN, (T) + 2, 0)                            \
        PH_OPEN; mf16(a0, bfr, 0); PH_CL                                 \
        rdA(a1, pa_, slot0_, 1);                                         \
        if (DO_WR) WRB_HALF(BRC, nbuf_, 0)                               \
        PH_OPEN; mf16(a1, bfr, 1); PH_CL                                 \
        rdB(bfr, pb_, slot1_);                                           \
        rdA(a1, pa_, slot1_, 1);                                         \
        if (DO_LDB) LDB_HALF(BRN, (T) + 2, 4)                            \
        PH_OPEN; mf16(a1, bfr, 1); PH_CL                                 \
        rdA(a0, pa_, slot1_, 0);                                         \
        if (DO_WR) WRB_HALF(BRC, nbuf_, 2)                               \
        PH_OPEN; mf16(a0, bfr, 0); PH_CL                                 \
        asm volatile("s_waitcnt vmcnt(" VB ") lgkmcnt(0)" ::: "memory"); \
        __builtin_amdgcn_sched_barrier(0);                               \
        __builtin_amdgcn_s_barrier();                                    \
        __builtin_amdgcn_sched_barrier(0);                               \
    }

// ---------------- x (fp32) -> bf16 ----------------
__global__ void cvt_x_kernel(const float* __restrict__ x, unsigned short* __restrict__ xb) {
    int i = blockIdx.x * blockDim.x + threadIdx.x;
    float4 v = reinterpret_cast<const float4*>(x)[i];
    ushort4 o;
    o.x = f2bf(v.x); o.y = f2bf(v.y); o.z = f2bf(v.z); o.w = f2bf(v.w);
    reinterpret_cast<ushort4*>(xb)[i] = o;
}

// ---------------- router: fp64 logits, softmax, top-2, lists ----------------
__global__ void router_kernel(const float* __restrict__ x, const float* __restrict__ gw,
                              float* __restrict__ topw, int* __restrict__ cnt,
                              int* __restrict__ list) {
    int t = blockIdx.x;
    int lane = threadIdx.x;
    const float* xt = x + (size_t)t * H;
    double acc[NE];
#pragma unroll
    for (int e = 0; e < NE; ++e) acc[e] = 0.0;
    for (int h = lane; h < H; h += 64) {
        float xv = xt[h];
#pragma unroll
        for (int e = 0; e < NE; ++e) acc[e] += (double)xv * (double)gw[e * H + h];
    }
#pragma unroll
    for (int e = 0; e < NE; ++e) {
#pragma unroll
        for (int off = 32; off > 0; off >>= 1)
            acc[e] += __shfl_xor(acc[e], off, 64);
    }
    if (lane == 0) {
        double mx = acc[0];
#pragma unroll
        for (int e = 1; e < NE; ++e) mx = acc[e] > mx ? acc[e] : mx;
        double ex[NE], s = 0.0;
#pragma unroll
        for (int e = 0; e < NE; ++e) { ex[e] = exp(acc[e] - mx); s += ex[e]; }
        int e0 = 0; double b0 = ex[0];
#pragma unroll
        for (int e = 1; e < NE; ++e) if (ex[e] > b0) { b0 = ex[e]; e0 = e; }
        int e1 = -1; double b1 = -1.0;
#pragma unroll
        for (int e = 0; e < NE; ++e) if (e != e0 && ex[e] > b1) { b1 = ex[e]; e1 = e; }
        float p0 = (float)(b0 / s), p1 = (float)(b1 / s);
        float w0 = p0 / (p0 + p1), w1 = p1 / (p0 + p1);
        topw[t * 2 + 0] = w0;
        topw[t * 2 + 1] = w1;
        int pos0 = atomicAdd(&cnt[e0], 1); list[e0 * TT + pos0] = t * 2 + 0;
        int pos1 = atomicAdd(&cnt[e1], 1); list[e1 * TT + pos1] = t * 2 + 1;
    }
}

// ---------------- tile map (256-row tiles at [20..39]) ----------------
__global__ void setup_kernel(const int* __restrict__ cnt, int* __restrict__ tmap) {
    if (threadIdx.x == 0) {
        int a128 = 0, a256 = 0;
        tmap[0] = 0; tmap[20] = 0;
        for (int g = 0; g < 9; ++g) {
            int rows = (g == 0) ? TT : cnt[g - 1];
            tmap[10 + g] = rows;
            tmap[30 + g] = rows;
            a128 += (rows + 127) >> 7;
            a256 += (rows + 255) >> 8;
            tmap[g + 1] = a128;
            tmap[20 + g + 1] = a256;
        }
        tmap[19] = 0; tmap[39] = 0;
    }
}

// ============ grouped GEMM1: 256x256, BK=64, fold-convert, 1-barrier/K-tile ===========
__global__ __launch_bounds__(512)
void gemm1_kernel(const unsigned short* __restrict__ xb,
                  const float* __restrict__ base_gu,
                  const float* __restrict__ exp_gu,
                  const int* __restrict__ tmap,
                  const int* __restrict__ list,
                  unsigned short* __restrict__ actB,
                  unsigned short* __restrict__ actE) {
    __shared__ unsigned short lds_a[2][256 * 64];
    __shared__ unsigned short lds_b[2][256 * 64];
    __shared__ int s_arow[256];
    __shared__ int s_orow[256];
    __shared__ int sh[20];

    int tid = threadIdx.x;
    if (tid < 20) sh[tid] = tmap[20 + tid];
    __syncthreads();
    int bid = blockIdx.x;
    int virt = (bid & 7) * 176 + (bid >> 3);     // 1408 = 8*176; jcols contiguous per XCD
    int jcol = virt >> 5;                        // 0..43
    int rt = virt & 31;
    if (rt >= sh[9]) return;
    int g = 0;
    while (rt >= sh[g + 1]) ++g;
    int rows_g = sh[10 + g];
    int row0 = (rt - sh[g]) * 256;
    int n0a = jcol * 128;                        // act-col base

    if (tid < 256) {
        int r = row0 + tid;
        int arow = 0, orow = 0;
        if (r < rows_g) {
            if (g == 0) { arow = r; orow = r; }
            else { int e = list[(g - 1) * TT + r]; arow = e >> 1; orow = e; }
        }
        s_arow[tid] = arow;
        s_orow[tid] = orow;
    }
    __syncthreads();

    const float* W = (g == 0) ? base_gu : (exp_gu + (size_t)(g - 1) * H * LDW1);
    unsigned short* actPtr = (g == 0) ? actB : actE;
    const size_t BST = LDW1;

    // A staging sources (4 gloads/tile; chunk = i*512+tid -> row=chunk>>3, kc=chunk&7)
    const unsigned short* asrc[4];
#pragma unroll
    for (int i = 0; i < 4; ++i) {
        int chunk = i * 512 + tid;
        int rl = chunk >> 3, kc = chunk & 7;
        asrc[i] = xb + (size_t)s_arow[rl] * H + ((kc ^ (rl & 7)) << 3);
    }
    int dstoff = (tid >> 6) * 1024;

    // B fp32 staging: ks = wave (k-rows ks*8..+7), cb = lane; 4 spread cols
    int ks = tid >> 6, cb = tid & 63;
    const float* bp[4];
    int bwaddr[4];
#pragma unroll
    for (int j = 0; j < 4; ++j) {
        int rl = cb + 64 * j;
        int wcol = (((rl >> 5) & 1) ? IDIM : 0) + n0a + ((rl >> 6) << 5) + (rl & 31);
        bp[j] = W + (size_t)(ks * 8) * LDW1 + wcol;
        bwaddr[j] = rl * 128 + ((ks ^ (cb & 7)) << 4);
    }

    auto issueA = [&](int kt, int buf) {
#pragma unroll
        for (int i = 0; i < 4; ++i)
            gload_lds16(asrc[i] + kt * 64, (char*)lds_a[buf] + i * 8192 + dstoff);
    };

    int wave = tid >> 6, lane = tid & 63;
    int wr = wave >> 2, wc = wave & 3;
    int arow0 = wr * 128 + (lane & 15);
    int bcol0 = wc * 64 + (lane & 15);
    int lxor = lane & 7;
    int kq = lane >> 4;

    f32x4 acc[8][4];
#pragma unroll
    for (int fm = 0; fm < 8; ++fm)
#pragma unroll
        for (int fn = 0; fn < 4; ++fn)
            acc[fm][fn] = (f32x4)(0.0f);

    bf16x8 a0[4], a1[4], bfr[4];
    auto rdA = [&](bf16x8* d, const char* pa, int slot, int fmh) {
#pragma unroll
        for (int i = 0; i < 4; ++i)
            d[i] = *reinterpret_cast<const bf16x8*>(pa + (arow0 + fmh * 64 + i * 16) * 128 + slot);
    };
    auto rdB = [&](bf16x8* d, const char* pb, int slot) {
#pragma unroll
        for (int fn = 0; fn < 4; ++fn)
            d[fn] = *reinterpret_cast<const bf16x8*>(pb + (bcol0 + fn * 16) * 128 + slot);
    };
    auto mf16 = [&](bf16x8* af, bf16x8* bf, int fmh) {
#pragma unroll
        for (int fn = 0; fn < 4; ++fn)
#pragma unroll
            for (int i = 0; i < 4; ++i)
                acc[fmh * 4 + i][fn] = __builtin_amdgcn_mfma_f32_16x16x32_bf16(
                    af[i], bf[fn], acc[fmh * 4 + i][fn], 0, 0, 0);
    };

    float brA[8][4], brB[8][4];

    // prologue: A(0)+B(0) staged; B(1) in brA
    issueA(0, 0);
    LDB_HALF(brB, 0, 0) LDB_HALF(brB, 0, 4)
    WRB_HALF(brB, 0, 0) WRB_HALF(brB, 0, 2)     // implicit waits drain B(0)+older A(0)
    LDB_HALF(brA, 1, 0) LDB_HALF(brA, 1, 4)
    asm volatile("s_waitcnt lgkmcnt(0)" ::: "memory");
    __builtin_amdgcn_sched_barrier(0);
    __builtin_amdgcn_s_barrier();
    __builtin_amdgcn_sched_barrier(0);

    for (int t = 0; t + 3 < NK1; t += 2) {
        TILE_F(t, brA, brB, true, true, true, "32")
        TILE_F(t + 1, brB, brA, true, true, true, "32")
    }
    TILE_F(NK1 - 2, brA, brB, true, false, true, "0")
    TILE_F(NK1 - 1, brB, brA, false, false, false, "63")

    int cq = lane >> 4, cr = lane & 15;
#pragma unroll
    for (int fm = 0; fm < 8; ++fm) {
#pragma unroll
        for (int r = 0; r < 4; ++r) {
            int rloc = wr * 128 + fm * 16 + cq * 4 + r;
            if (row0 + rloc < rows_g) {
                size_t orow = (size_t)s_orow[rloc];
#pragma unroll
                for (int fn = 0; fn < 2; ++fn) {
                    float gv = acc[fm][fn][r];
                    float uv = acc[fm][fn + 2][r];
                    float sv = gv / (1.0f + __expf(-gv));
                    int col = n0a + wc * 32 + fn * 16 + cr;
                    actPtr[orow * IDIM + col] = f2bf(sv * uv);
                }
            }
        }
    }
}

// ============ grouped GEMM2: 256x256, BK=64, fold-convert, 1-barrier/K-tile ===========
__global__ __launch_bounds__(512)
void gemm2_kernel(const unsigned short* __restrict__ actB,
                  const unsigned short* __restrict__ actE,
                  const float* __restrict__ base_dn,
                  const float* __restrict__ exp_dn,
                  const int* __restrict__ tmap,
                  const int* __restrict__ list,
                  float* __restrict__ outB,
                  float* __restrict__ yslot) {
    __shared__ unsigned short lds_a[2][256 * 64];
    __shared__ unsigned short lds_b[2][256 * 64];
    __shared__ int s_row[256];
    __shared__ int sh[20];

    int tid = threadIdx.x;
    if (tid < 20) sh[tid] = tmap[20 + tid];
    __syncthreads();
    int bid = blockIdx.x;
    int virt = (bid & 7) * 32 + (bid >> 3);      // 256 = 8*32; one col-strip per XCD
    int jcol = virt >> 5;                        // 0..7
    int rt = virt & 31;
    if (rt >= sh[9]) return;
    int g = 0;
    while (rt >= sh[g + 1]) ++g;
    int rows_g = sh[10 + g];
    int row0 = (rt - sh[g]) * 256;
    int n0 = jcol * 256;

    if (tid < 256) {
        int r = row0 + tid;
        int rowi = 0;
        if (r < rows_g) rowi = (g == 0) ? r : list[(g - 1) * TT + r];
        s_row[tid] = rowi;
    }
    __syncthreads();

    const unsigned short* abase = (g == 0) ? actB : actE;
    const float* W = (g == 0) ? base_dn : (exp_dn + (size_t)(g - 1) * IDIM * H);
    float* obase = (g == 0) ? outB : yslot;
    const size_t BST = H;

    const unsigned short* asrc[4];
#pragma unroll
    for (int i = 0; i < 4; ++i) {
        int chunk = i * 512 + tid;
        int rl = chunk >> 3, kc = chunk & 7;
        asrc[i] = abase + (size_t)s_row[rl] * IDIM + ((kc ^ (rl & 7)) << 3);
    }
    int dstoff = (tid >> 6) * 1024;

    int ks = tid >> 6, cb = tid & 63;
    const float* bp[4];
    int bwaddr[4];
#pragma unroll
    for (int j = 0; j < 4; ++j) {
        int rl = cb + 64 * j;
        bp[j] = W + (size_t)(ks * 8) * H + n0 + rl;
        bwaddr[j] = rl * 128 + ((ks ^ (cb & 7)) << 4);
    }

    auto issueA = [&](int kt, int buf) {
#pragma unroll
        for (int i = 0; i < 4; ++i)
            gload_lds16(asrc[i] + kt * 64, (char*)lds_a[buf] + i * 8192 + dstoff);
    };

    int wave = tid >> 6, lane = tid & 63;
    int wr = wave >> 2, wc = wave & 3;
    int arow0 = wr * 128 + (lane & 15);
    int bcol0 = wc * 64 + (lane & 15);
    int lxor = lane & 7;
    int kq = lane >> 4;

    f32x4 acc[8][4];
#pragma unroll
    for (int fm = 0; fm < 8; ++fm)
#pragma unroll
        for (int fn = 0; fn < 4; ++fn)
            acc[fm][fn] = (f32x4)(0.0f);

    bf16x8 a0[4], a1[4], bfr[4];
    auto rdA = [&](bf16x8* d, const char* pa, int slot, int fmh) {
#pragma unroll
        for (int i = 0; i < 4; ++i)
            d[i] = *reinterpret_cast<const bf16x8*>(pa + (arow0 + fmh * 64 + i * 16) * 128 + slot);
    };
    auto rdB = [&](bf16x8* d, const char* pb, int slot) {
#pragma unroll
        for (int fn = 0; fn < 4; ++fn)
            d[fn] = *reinterpret_cast<const bf16x8*>(pb + (bcol0 + fn * 16) * 128 + slot);
    };
    auto mf16 = [&](bf16x8* af, bf16x8* bf, int fmh) {
#pragma unroll
        for (int fn = 0; fn < 4; ++fn)
#pragma unroll
            for (int i = 0; i < 4; ++i)
                acc[fmh * 4 + i][fn] = __builtin_amdgcn_mfma_f32_16x16x32_bf16(
                    af[i], bf[fn], acc[fmh * 4 + i][fn], 0, 0, 0);
    };

    float brA[8][4], brB[8][4];

    issueA(0, 0);
    LDB_HALF(brB, 0, 0) LDB_HALF(brB, 0, 4)
    WRB_HALF(brB, 0, 0) WRB_HALF(brB, 0, 2)
    LDB_HALF(brA, 1, 0) LDB_HALF(brA, 1, 4)
    asm volatile("s_waitcnt lgkmcnt(0)" ::: "memory");
    __builtin_amdgcn_sched_barrier(0);
    __builtin_amdgcn_s_barrier();
    __builtin_amdgcn_sched_barrier(0);

    for (int t = 0; t + 3 < NK2; t += 2) {
        TILE_F(t, brA, brB, true, true, true, "32")
        TILE_F(t + 1, brB, brA, true, true, true, "32")
    }
    TILE_F(NK2 - 2, brA, brB, true, false, true, "0")
    TILE_F(NK2 - 1, brB, brA, false, false, false, "63")

    int cq = lane >> 4, cr = lane & 15;
#pragma unroll
    for (int fm = 0; fm < 8; ++fm) {
#pragma unroll
        for (int r = 0; r < 4; ++r) {
            int rloc = wr * 128 + fm * 16 + cq * 4 + r;
            if (row0 + rloc < rows_g) {
                size_t orow = (size_t)s_row[rloc];
#pragma unroll
                for (int fn = 0; fn < 4; ++fn) {
                    int col = n0 + wc * 64 + fn * 16 + cr;
                    obase[orow * H + col] = acc[fm][fn][r];
                }
            }
        }
    }
}

// ---------------- combine: out += w0*y0 + w1*y1 ----------------
__global__ void combine_kernel(float* __restrict__ out, const float* __restrict__ yslot,
                               const float* __restrict__ topw) {
    int i = blockIdx.x * blockDim.x + threadIdx.x;
    int t = i >> 9;
    int c = (i & 511) << 2;
    float w0 = topw[t * 2], w1 = topw[t * 2 + 1];
    float4 y0 = *reinterpret_cast<const float4*>(yslot + ((size_t)(2 * t) * H + c));
    float4 y1 = *reinterpret_cast<const float4*>(yslot + ((size_t)(2 * t + 1) * H + c));
    float4* po = reinterpret_cast<float4*>(out + ((size_t)t * H + c));
    float4 o = *po;
    o.x += w0 * y0.x + w1 * y1.x;
    o.y += w0 * y0.y + w1 * y1.y;
    o.z += w0 * y0.z + w1 * y1.z;
    o.w += w0 * y0.w + w1 * y1.w;
    *po = o;
}

extern "C" void kernel_launch(void* const* d_in, const int* in_sizes, int n_in,
                              void* d_out, int out_size, void* d_ws, size_t ws_size,
                              hipStream_t stream) {
    const float* x   = (const float*)d_in[0];
    const float* gw  = (const float*)d_in[1];
    const float* bgu = (const float*)d_in[2];
    const float* bdn = (const float*)d_in[3];
    const float* egu = (const float*)d_in[4];
    const float* edn = (const float*)d_in[5];
    float* out = (float*)d_out;
    char* ws = (char*)d_ws;

    unsigned short* xb   = (unsigned short*)(ws + 0);          //  8,388,608 B
    unsigned short* actB = (unsigned short*)(ws + 8388608);    // 23,068,672 B
    unsigned short* actE = (unsigned short*)(ws + 31457280);   // 46,137,344 B
    float* yslot         = (float*)(ws + 77594624);            // 33,554,432 B
    float* topw          = (float*)(ws + 111149056);
    int* cnt             = (int*)(ws + 111165440);
    int* list            = (int*)(ws + 111165696);
    int* tmap            = (int*)(ws + 111231232);

    hipMemsetAsync(cnt, 0, NE * sizeof(int), stream);
    cvt_x_kernel<<<4096, 256, 0, stream>>>(x, xb);
    router_kernel<<<TT, 64, 0, stream>>>(x, gw, topw, cnt, list);
    setup_kernel<<<1, 64, 0, stream>>>(cnt, tmap);
    // gemm1: 44 col-strips x up-to-32 row-tiles, XCD-pinned
    gemm1_kernel<<<1408, 512, 0, stream>>>(xb, bgu, egu, tmap, list, actB, actE);
    // gemm2: 8 col-strips x up-to-32 row-tiles
    gemm2_kernel<<<256, 512, 0, stream>>>(actB, actE, bdn, edn, tmap, list, out, yslot);
    combine_kernel<<<4096, 256, 0, stream>>>(out, yslot, topw);
}

// Round 18
// 764.779 us; speedup vs baseline: 3.2865x; 1.0111x over previous
//
#include <hip/hip_runtime.h>
#include <math.h>

#define H 2048
#define IDIM 5632
#define NE 8
#define TT 2048            // tokens = 2*1024
#define LDW1 (2 * IDIM)    // 11264
#define NK1 (H / 64)       // 32
#define NK2 (IDIM / 64)    // 88

typedef __bf16 bf16x8 __attribute__((ext_vector_type(8)));
typedef float f32x4 __attribute__((ext_vector_type(4)));

__device__ __forceinline__ unsigned short f2bf(float f) {
    unsigned int u = __builtin_bit_cast(unsigned int, f);
    u += 0x7FFFu + ((u >> 16) & 1u);   // round-to-nearest-even
    return (unsigned short)(u >> 16);
}

// HW convert: compiler emits v_cvt_pk_bf16_f32 from paired casts (RTNE)
__device__ __forceinline__ unsigned int pk2(float a, float b) {
    __bf16 x = (__bf16)a, y = (__bf16)b;
    unsigned short lo = __builtin_bit_cast(unsigned short, x);
    unsigned short hi = __builtin_bit_cast(unsigned short, y);
    return (unsigned int)lo | ((unsigned int)hi << 16);
}

__device__ __forceinline__ void gload_lds16(const void* g, void* l) {
    __builtin_amdgcn_global_load_lds(
        (const __attribute__((address_space(1))) void*)g,
        (__attribute__((address_space(3))) void*)l, 16, 0, 0);
}

// per-phase fences: wave-local only. PH_CL has NO sched_barrier -> next phase's
// frag reads may hoist into this MFMA cluster (latency hiding).
#define PH_OPEN                                         \
    asm volatile("s_waitcnt lgkmcnt(0)" ::: "memory");  \
    __builtin_amdgcn_sched_barrier(0);                  \
    __builtin_amdgcn_s_setprio(1);
#define PH_CL                                           \
    __builtin_amdgcn_s_setprio(0);

// 16 dword loads: rows rlo..rlo+3 x 4 spread cols (static indices only)
#define LDB_HALF(BR, kt, rlo)                                            \
    {                                                                    \
        _Pragma("unroll")                                                \
        for (int r_ = 0; r_ < 4; ++r_) {                                 \
            _Pragma("unroll")                                            \
            for (int j_ = 0; j_ < 4; ++j_)                               \
                BR[(rlo) + r_][j_] =                                     \
                    bp[j_][(size_t)((kt) * 64 + (rlo) + r_) * BST];      \
        }                                                                \
    }
// cvt+pack+swizzled b128 writes, chunks jlo..jlo+1 (conflict-free, r12-verified)
#define WRB_HALF(BR, nb, jlo)                                            \
    {                                                                    \
        char* pbw_ = (char*)lds_b[nb];                                   \
        _Pragma("unroll")                                                \
        for (int j_ = (jlo); j_ < (jlo) + 2; ++j_) {                     \
            uint4 pk_;                                                   \
            pk_.x = pk2(BR[0][j_], BR[1][j_]);                           \
            pk_.y = pk2(BR[2][j_], BR[3][j_]);                           \
            pk_.z = pk2(BR[4][j_], BR[5][j_]);                           \
            pk_.w = pk2(BR[6][j_], BR[7][j_]);                           \
            *reinterpret_cast<uint4*>(pbw_ + bwaddr[j_]) = pk_;          \
        }                                                                \
    }

// 4-phase fold K-tile, ONE block barrier per tile (boundary only).
// Frag reads live with previous MFMA region; stage ops isolated by sched_barrier.
#define TILE_F(T, BRC, BRN, DO_STA, DO_LDB, DO_WR, VB)                   \
    {                                                                    \
        const int buf_ = (T) & 1, nbuf_ = buf_ ^ 1;                      \
        const char* pa_ = (const char*)lds_a[buf_];                      \
        const char* pb_ = (const char*)lds_b[buf_];                      \
        int slot0_ = (kq ^ lxor) << 4;                                   \
        int slot1_ = ((kq + 4) ^ lxor) << 4;                             \
        rdB(bfr, pb_, slot0_);                                           \
        rdA(a0, pa_, slot0_, 0);                                         \
        __builtin_amdgcn_sched_barrier(0);                               \
        if (DO_STA) issueA((T) + 1, nbuf_);                              \
        if (DO_LDB) LDB_HALF(BRN, (T) + 2, 0)                            \
        PH_OPEN; mf16(a0, bfr, 0); PH_CL                                 \
        rdA(a1, pa_, slot0_, 1);                                         \
        __builtin_amdgcn_sched_barrier(0);                               \
        if (DO_WR) WRB_HALF(BRC, nbuf_, 0)                               \
        PH_OPEN; mf16(a1, bfr, 1); PH_CL                                 \
        rdB(bfr, pb_, slot1_);                                           \
        rdA(a1, pa_, slot1_, 1);                                         \
        __builtin_amdgcn_sched_barrier(0);                               \
        if (DO_LDB) LDB_HALF(BRN, (T) + 2, 4)                            \
        PH_OPEN; mf16(a1, bfr, 1); PH_CL                                 \
        rdA(a0, pa_, slot1_, 0);                                         \
        __builtin_amdgcn_sched_barrier(0);                               \
        if (DO_WR) WRB_HALF(BRC, nbuf_, 2)                               \
        PH_OPEN; mf16(a0, bfr, 0); PH_CL                                 \
        __builtin_amdgcn_sched_barrier(0);                               \
        asm volatile("s_waitcnt vmcnt(" VB ") lgkmcnt(0)" ::: "memory"); \
        __builtin_amdgcn_sched_barrier(0);                               \
        __builtin_amdgcn_s_barrier();                                    \
        __builtin_amdgcn_sched_barrier(0);                               \
    }

// ---------------- router: fp64 logits, softmax, top-2, lists + fused x->bf16 ---------
__global__ void router_kernel(const float* __restrict__ x, const float* __restrict__ gw,
                              float* __restrict__ topw, int* __restrict__ cnt,
                              int* __restrict__ list, unsigned short* __restrict__ xb) {
    int t = blockIdx.x;
    int lane = threadIdx.x;
    const float* xt = x + (size_t)t * H;
    unsigned short* xbt = xb + (size_t)t * H;
    double acc[NE];
#pragma unroll
    for (int e = 0; e < NE; ++e) acc[e] = 0.0;
    for (int h = lane; h < H; h += 64) {
        float xv = xt[h];
        xbt[h] = f2bf(xv);
#pragma unroll
        for (int e = 0; e < NE; ++e) acc[e] += (double)xv * (double)gw[e * H + h];
    }
#pragma unroll
    for (int e = 0; e < NE; ++e) {
#pragma unroll
        for (int off = 32; off > 0; off >>= 1)
            acc[e] += __shfl_xor(acc[e], off, 64);
    }
    if (lane == 0) {
        double mx = acc[0];
#pragma unroll
        for (int e = 1; e < NE; ++e) mx = acc[e] > mx ? acc[e] : mx;
        double ex[NE], s = 0.0;
#pragma unroll
        for (int e = 0; e < NE; ++e) { ex[e] = exp(acc[e] - mx); s += ex[e]; }
        int e0 = 0; double b0 = ex[0];
#pragma unroll
        for (int e = 1; e < NE; ++e) if (ex[e] > b0) { b0 = ex[e]; e0 = e; }
        int e1 = -1; double b1 = -1.0;
#pragma unroll
        for (int e = 0; e < NE; ++e) if (e != e0 && ex[e] > b1) { b1 = ex[e]; e1 = e; }
        float p0 = (float)(b0 / s), p1 = (float)(b1 / s);
        float w0 = p0 / (p0 + p1), w1 = p1 / (p0 + p1);
        topw[t * 2 + 0] = w0;
        topw[t * 2 + 1] = w1;
        int pos0 = atomicAdd(&cnt[e0], 1); list[e0 * TT + pos0] = t * 2 + 0;
        int pos1 = atomicAdd(&cnt[e1], 1); list[e1 * TT + pos1] = t * 2 + 1;
    }
}

// ---------------- tile map (256-row tiles at [20..39]) ----------------
__global__ void setup_kernel(const int* __restrict__ cnt, int* __restrict__ tmap) {
    if (threadIdx.x == 0) {
        int a128 = 0, a256 = 0;
        tmap[0] = 0; tmap[20] = 0;
        for (int g = 0; g < 9; ++g) {
            int rows = (g == 0) ? TT : cnt[g - 1];
            tmap[10 + g] = rows;
            tmap[30 + g] = rows;
            a128 += (rows + 127) >> 7;
            a256 += (rows + 255) >> 8;
            tmap[g + 1] = a128;
            tmap[20 + g + 1] = a256;
        }
        tmap[19] = 0; tmap[39] = 0;
    }
}

// ============ grouped GEMM1: 256x256, BK=64, fold-convert, 1-barrier/K-tile ===========
__global__ __launch_bounds__(512)
void gemm1_kernel(const unsigned short* __restrict__ xb,
                  const float* __restrict__ base_gu,
                  const float* __restrict__ exp_gu,
                  const int* __restrict__ tmap,
                  const int* __restrict__ list,
                  unsigned short* __restrict__ actB,
                  unsigned short* __restrict__ actE) {
    __shared__ unsigned short lds_a[2][256 * 64];
    __shared__ unsigned short lds_b[2][256 * 64];
    __shared__ int s_arow[256];
    __shared__ int s_orow[256];
    __shared__ int sh[20];

    int tid = threadIdx.x;
    if (tid < 20) sh[tid] = tmap[20 + tid];
    __syncthreads();
    int bid = blockIdx.x;
    int virt = (bid & 7) * 176 + (bid >> 3);     // 1408 = 8*176; jcols contiguous per XCD
    int jcol = virt >> 5;                        // 0..43
    int rt = virt & 31;
    if (rt >= sh[9]) return;
    int g = 0;
    while (rt >= sh[g + 1]) ++g;
    int rows_g = sh[10 + g];
    int row0 = (rt - sh[g]) * 256;
    int n0a = jcol * 128;                        // act-col base

    if (tid < 256) {
        int r = row0 + tid;
        int arow = 0, orow = 0;
        if (r < rows_g) {
            if (g == 0) { arow = r; orow = r; }
            else { int e = list[(g - 1) * TT + r]; arow = e >> 1; orow = e; }
        }
        s_arow[tid] = arow;
        s_orow[tid] = orow;
    }
    __syncthreads();

    const float* W = (g == 0) ? base_gu : (exp_gu + (size_t)(g - 1) * H * LDW1);
    unsigned short* actPtr = (g == 0) ? actB : actE;
    const size_t BST = LDW1;

    // A staging sources (4 gloads/tile; chunk = i*512+tid -> row=chunk>>3, kc=chunk&7)
    const unsigned short* asrc[4];
#pragma unroll
    for (int i = 0; i < 4; ++i) {
        int chunk = i * 512 + tid;
        int rl = chunk >> 3, kc = chunk & 7;
        asrc[i] = xb + (size_t)s_arow[rl] * H + ((kc ^ (rl & 7)) << 3);
    }
    int dstoff = (tid >> 6) * 1024;

    // B fp32 staging: ks = wave (k-rows ks*8..+7), cb = lane; 4 spread cols
    int ks = tid >> 6, cb = tid & 63;
    const float* bp[4];
    int bwaddr[4];
#pragma unroll
    for (int j = 0; j < 4; ++j) {
        int rl = cb + 64 * j;
        int wcol = (((rl >> 5) & 1) ? IDIM : 0) + n0a + ((rl >> 6) << 5) + (rl & 31);
        bp[j] = W + (size_t)(ks * 8) * LDW1 + wcol;
        bwaddr[j] = rl * 128 + ((ks ^ (cb & 7)) << 4);
    }

    auto issueA = [&](int kt, int buf) {
#pragma unroll
        for (int i = 0; i < 4; ++i)
            gload_lds16(asrc[i] + kt * 64, (char*)lds_a[buf] + i * 8192 + dstoff);
    };

    int wave = tid >> 6, lane = tid & 63;
    int wr = wave >> 2, wc = wave & 3;
    int arow0 = wr * 128 + (lane & 15);
    int bcol0 = wc * 64 + (lane & 15);
    int lxor = lane & 7;
    int kq = lane >> 4;

    f32x4 acc[8][4];
#pragma unroll
    for (int fm = 0; fm < 8; ++fm)
#pragma unroll
        for (int fn = 0; fn < 4; ++fn)
            acc[fm][fn] = (f32x4)(0.0f);

    bf16x8 a0[4], a1[4], bfr[4];
    auto rdA = [&](bf16x8* d, const char* pa, int slot, int fmh) {
#pragma unroll
        for (int i = 0; i < 4; ++i)
            d[i] = *reinterpret_cast<const bf16x8*>(pa + (arow0 + fmh * 64 + i * 16) * 128 + slot);
    };
    auto rdB = [&](bf16x8* d, const char* pb, int slot) {
#pragma unroll
        for (int fn = 0; fn < 4; ++fn)
            d[fn] = *reinterpret_cast<const bf16x8*>(pb + (bcol0 + fn * 16) * 128 + slot);
    };
    auto mf16 = [&](bf16x8* af, bf16x8* bf, int fmh) {
#pragma unroll
        for (int fn = 0; fn < 4; ++fn)
#pragma unroll
            for (int i = 0; i < 4; ++i)
                acc[fmh * 4 + i][fn] = __builtin_amdgcn_mfma_f32_16x16x32_bf16(
                    af[i], bf[fn], acc[fmh * 4 + i][fn], 0, 0, 0);
    };

    float brA[8][4], brB[8][4];

    // prologue: A(0)+B(0) staged; B(1) in brA
    issueA(0, 0);
    LDB_HALF(brB, 0, 0) LDB_HALF(brB, 0, 4)
    WRB_HALF(brB, 0, 0) WRB_HALF(brB, 0, 2)     // implicit waits drain B(0)+older A(0)
    LDB_HALF(brA, 1, 0) LDB_HALF(brA, 1, 4)
    asm volatile("s_waitcnt lgkmcnt(0)" ::: "memory");
    __builtin_amdgcn_sched_barrier(0);
    __builtin_amdgcn_s_barrier();
    __builtin_amdgcn_sched_barrier(0);

    for (int t = 0; t + 3 < NK1; t += 2) {
        TILE_F(t, brA, brB, true, true, true, "32")
        TILE_F(t + 1, brB, brA, true, true, true, "32")
    }
    TILE_F(NK1 - 2, brA, brB, true, false, true, "0")
    TILE_F(NK1 - 1, brB, brA, false, false, false, "63")

    int cq = lane >> 4, cr = lane & 15;
#pragma unroll
    for (int fm = 0; fm < 8; ++fm) {
#pragma unroll
        for (int r = 0; r < 4; ++r) {
            int rloc = wr * 128 + fm * 16 + cq * 4 + r;
            if (row0 + rloc < rows_g) {
                size_t orow = (size_t)s_orow[rloc];
#pragma unroll
                for (int fn = 0; fn < 2; ++fn) {
                    float gv = acc[fm][fn][r];
                    float uv = acc[fm][fn + 2][r];
                    float sv = gv / (1.0f + __expf(-gv));
                    int col = n0a + wc * 32 + fn * 16 + cr;
                    actPtr[orow * IDIM + col] = f2bf(sv * uv);
                }
            }
        }
    }
}

// ============ grouped GEMM2: 256x256, BK=64, fold-convert, 1-barrier/K-tile ===========
__global__ __launch_bounds__(512)
void gemm2_kernel(const unsigned short* __restrict__ actB,
                  const unsigned short* __restrict__ actE,
                  const float* __restrict__ base_dn,
                  const float* __restrict__ exp_dn,
                  const int* __restrict__ tmap,
                  const int* __restrict__ list,
                  float* __restrict__ outB,
                  float* __restrict__ yslot) {
    __shared__ unsigned short lds_a[2][256 * 64];
    __shared__ unsigned short lds_b[2][256 * 64];
    __shared__ int s_row[256];
    __shared__ int sh[20];

    int tid = threadIdx.x;
    if (tid < 20) sh[tid] = tmap[20 + tid];
    __syncthreads();
    int bid = blockIdx.x;
    int virt = (bid & 7) * 32 + (bid >> 3);      // 256 = 8*32; one col-strip per XCD
    int jcol = virt >> 5;                        // 0..7
    int rt = virt & 31;
    if (rt >= sh[9]) return;
    int g = 0;
    while (rt >= sh[g + 1]) ++g;
    int rows_g = sh[10 + g];
    int row0 = (rt - sh[g]) * 256;
    int n0 = jcol * 256;

    if (tid < 256) {
        int r = row0 + tid;
        int rowi = 0;
        if (r < rows_g) rowi = (g == 0) ? r : list[(g - 1) * TT + r];
        s_row[tid] = rowi;
    }
    __syncthreads();

    const unsigned short* abase = (g == 0) ? actB : actE;
    const float* W = (g == 0) ? base_dn : (exp_dn + (size_t)(g - 1) * IDIM * H);
    float* obase = (g == 0) ? outB : yslot;
    const size_t BST = H;

    const unsigned short* asrc[4];
#pragma unroll
    for (int i = 0; i < 4; ++i) {
        int chunk = i * 512 + tid;
        int rl = chunk >> 3, kc = chunk & 7;
        asrc[i] = abase + (size_t)s_row[rl] * IDIM + ((kc ^ (rl & 7)) << 3);
    }
    int dstoff = (tid >> 6) * 1024;

    int ks = tid >> 6, cb = tid & 63;
    const float* bp[4];
    int bwaddr[4];
#pragma unroll
    for (int j = 0; j < 4; ++j) {
        int rl = cb + 64 * j;
        bp[j] = W + (size_t)(ks * 8) * H + n0 + rl;
        bwaddr[j] = rl * 128 + ((ks ^ (cb & 7)) << 4);
    }

    auto issueA = [&](int kt, int buf) {
#pragma unroll
        for (int i = 0; i < 4; ++i)
            gload_lds16(asrc[i] + kt * 64, (char*)lds_a[buf] + i * 8192 + dstoff);
    };

    int wave = tid >> 6, lane = tid & 63;
    int wr = wave >> 2, wc = wave & 3;
    int arow0 = wr * 128 + (lane & 15);
    int bcol0 = wc * 64 + (lane & 15);
    int lxor = lane & 7;
    int kq = lane >> 4;

    f32x4 acc[8][4];
#pragma unroll
    for (int fm = 0; fm < 8; ++fm)
#pragma unroll
        for (int fn = 0; fn < 4; ++fn)
            acc[fm][fn] = (f32x4)(0.0f);

    bf16x8 a0[4], a1[4], bfr[4];
    auto rdA = [&](bf16x8* d, const char* pa, int slot, int fmh) {
#pragma unroll
        for (int i = 0; i < 4; ++i)
            d[i] = *reinterpret_cast<const bf16x8*>(pa + (arow0 + fmh * 64 + i * 16) * 128 + slot);
    };
    auto rdB = [&](bf16x8* d, const char* pb, int slot) {
#pragma unroll
        for (int fn = 0; fn < 4; ++fn)
            d[fn] = *reinterpret_cast<const bf16x8*>(pb + (bcol0 + fn * 16) * 128 + slot);
    };
    auto mf16 = [&](bf16x8* af, bf16x8* bf, int fmh) {
#pragma unroll
        for (int fn = 0; fn < 4; ++fn)
#pragma unroll
            for (int i = 0; i < 4; ++i)
                acc[fmh * 4 + i][fn] = __builtin_amdgcn_mfma_f32_16x16x32_bf16(
                    af[i], bf[fn], acc[fmh * 4 + i][fn], 0, 0, 0);
    };

    float brA[8][4], brB[8][4];

    issueA(0, 0);
    LDB_HALF(brB, 0, 0) LDB_HALF(brB, 0, 4)
    WRB_HALF(brB, 0, 0) WRB_HALF(brB, 0, 2)
    LDB_HALF(brA, 1, 0) LDB_HALF(brA, 1, 4)
    asm volatile("s_waitcnt lgkmcnt(0)" ::: "memory");
    __builtin_amdgcn_sched_barrier(0);
    __builtin_amdgcn_s_barrier();
    __builtin_amdgcn_sched_barrier(0);

    for (int t = 0; t + 3 < NK2; t += 2) {
        TILE_F(t, brA, brB, true, true, true, "32")
        TILE_F(t + 1, brB, brA, true, true, true, "32")
    }
    TILE_F(NK2 - 2, brA, brB, true, false, true, "0")
    TILE_F(NK2 - 1, brB, brA, false, false, false, "63")

    int cq = lane >> 4, cr = lane & 15;
#pragma unroll
    for (int fm = 0; fm < 8; ++fm) {
#pragma unroll
        for (int r = 0; r < 4; ++r) {
            int rloc = wr * 128 + fm * 16 + cq * 4 + r;
            if (row0 + rloc < rows_g) {
                size_t orow = (size_t)s_row[rloc];
#pragma unroll
                for (int fn = 0; fn < 4; ++fn) {
                    int col = n0 + wc * 64 + fn * 16 + cr;
                    obase[orow * H + col] = acc[fm][fn][r];
                }
            }
        }
    }
}

// ---------------- combine: out += w0*y0 + w1*y1 ----------------
__global__ void combine_kernel(float* __restrict__ out, const float* __restrict__ yslot,
                               const float* __restrict__ topw) {
    int i = blockIdx.x * blockDim.x + threadIdx.x;
    int t = i >> 9;
    int c = (i & 511) << 2;
    float w0 = topw[t * 2], w1 = topw[t * 2 + 1];
    float4 y0 = *reinterpret_cast<const float4*>(yslot + ((size_t)(2 * t) * H + c));
    float4 y1 = *reinterpret_cast<const float4*>(yslot + ((size_t)(2 * t + 1) * H + c));
    float4* po = reinterpret_cast<float4*>(out + ((size_t)t * H + c));
    float4 o = *po;
    o.x += w0 * y0.x + w1 * y1.x;
    o.y += w0 * y0.y + w1 * y1.y;
    o.z += w0 * y0.z + w1 * y1.z;
    o.w += w0 * y0.w + w1 * y1.w;
    *po = o;
}

extern "C" void kernel_launch(void* const* d_in, const int* in_sizes, int n_in,
                              void* d_out, int out_size, void* d_ws, size_t ws_size,
                              hipStream_t stream) {
    const float* x   = (const float*)d_in[0];
    const float* gw  = (const float*)d_in[1];
    const float* bgu = (const float*)d_in[2];
    const float* bdn = (const float*)d_in[3];
    const float* egu = (const float*)d_in[4];
    const float* edn = (const float*)d_in[5];
    float* out = (float*)d_out;
    char* ws = (char*)d_ws;

    unsigned short* xb   = (unsigned short*)(ws + 0);          //  8,388,608 B
    unsigned short* actB = (unsigned short*)(ws + 8388608);    // 23,068,672 B
    unsigned short* actE = (unsigned short*)(ws + 31457280);   // 46,137,344 B
    float* yslot         = (float*)(ws + 77594624);            // 33,554,432 B
    float* topw          = (float*)(ws + 111149056);
    int* cnt             = (int*)(ws + 111165440);
    int* list            = (int*)(ws + 111165696);
    int* tmap            = (int*)(ws + 111231232);

    hipMemsetAsync(cnt, 0, NE * sizeof(int), stream);
    router_kernel<<<TT, 64, 0, stream>>>(x, gw, topw, cnt, list, xb);
    setup_kernel<<<1, 64, 0, stream>>>(cnt, tmap);
    // gemm1: 44 col-strips x up-to-32 row-tiles, XCD-pinned
    gemm1_kernel<<<1408, 512, 0, stream>>>(xb, bgu, egu, tmap, list, actB, actE);
    // gemm2: 8 col-strips x up-to-32 row-tiles
    gemm2_kernel<<<256, 512, 0, stream>>>(actB, actE, bdn, edn, tmap, list, out, yslot);
    combine_kernel<<<4096, 256, 0, stream>>>(out, yslot, topw);
}